// Round 6
// baseline (538.170 us; speedup 1.0000x reference)
//
#include <hip/hip_runtime.h>

#define N_NODES 100000
#define KK 5
#define CC 16
#define EE 3200000
#define NXCC 8

#define NB 16                // row buckets
#define ROWS_PB 6250         // N_NODES / NB
#define CAP 1020000          // per-bucket global capacity (mean 1M, +20 sigma)
#define BPB 64               // accum blocks per bucket
#define CHUNK 5120           // edges per scatter block: 3125 * 5120 = 16,000,000
#define NCHUNK 3125
#define ROUND 1024           // edges buffered per round (256 thr * 4)
#define NROUND 5             // CHUNK / ROUND
#define BCAP 160             // LDS entries per bucket per round (mean 64, +12 sigma)

__device__ __forceinline__ int xcc_id() {
    int x;
    asm volatile("s_getreg_b32 %0, hwreg(HW_REG_XCC_ID)" : "=s"(x));
    return x & (NXCC - 1);
}

// Kernel 1: Zt[k*N + n] = sum_c X[n,c] * h[c,k]
__global__ void compute_z_kernel(const float* __restrict__ X,
                                 const float* __restrict__ h,
                                 float* __restrict__ Zt) {
    int n = blockIdx.x * blockDim.x + threadIdx.x;
    if (n >= N_NODES) return;
    const float4* Xr = (const float4*)(X + (size_t)n * CC);
    float4 x0 = Xr[0], x1 = Xr[1], x2 = Xr[2], x3 = Xr[3];
    float xv[CC] = {x0.x, x0.y, x0.z, x0.w, x1.x, x1.y, x1.z, x1.w,
                    x2.x, x2.y, x2.z, x2.w, x3.x, x3.y, x3.z, x3.w};
#pragma unroll
    for (int k = 0; k < KK; ++k) {
        float acc = 0.0f;
#pragma unroll
        for (int c = 0; c < CC; ++c) acc += xv[c] * h[c * KK + k];
        Zt[k * N_NODES + n] = acc;
    }
}

// Phase A (single pass): bucket edges via LDS staging, flush COALESCED.
// Per round of 1024 edges: buffer (row,contrib) per bucket in LDS, then one
// global cursor atomic per bucket and a lane-sequential window copy.
// 16M random 8B write-requests -> ~2M full-line coalesced writes.
__global__ void scatter_kernel(const int* __restrict__ rows,
                               const int* __restrict__ cols,
                               const float* __restrict__ vals,
                               const float* __restrict__ Zt,
                               int* __restrict__ cursor,       // NB counters, stride 16 ints
                               uint2* __restrict__ binned) {
    __shared__ uint2 lbuf[NB * BCAP];     // 20 KB
    __shared__ int   lcnt[NB];
    __shared__ int   gbase[NB];
    int tid = threadIdx.x;
    int cbase = blockIdx.x * CHUNK;

    for (int rd = 0; rd < NROUND; ++rd) {
        if (tid < NB) lcnt[tid] = 0;
        __syncthreads();

        int e = cbase + rd * ROUND + tid * 4;
        int k = e / EE;                            // int4 group shares k (EE%4==0)
        const float* Zk = Zt + (size_t)k * N_NODES;
        int4   r = *(const int4*)(rows + e);
        int4   c = *(const int4*)(cols + e);
        float4 v = *(const float4*)(vals + e);
        int   rr[4] = {r.x, r.y, r.z, r.w};
        float cb[4] = {v.x * Zk[c.x], v.y * Zk[c.y], v.z * Zk[c.z], v.w * Zk[c.w]};

#pragma unroll
        for (int i = 0; i < 4; ++i) {
            int b = rr[i] / ROWS_PB;
            uint2 ent = make_uint2((unsigned)rr[i], __float_as_uint(cb[i]));
            int pos = atomicAdd(&lcnt[b], 1);
            if (pos < BCAP) {
                lbuf[b * BCAP + pos] = ent;
            } else {                               // statistically never (mean 64, cap 160)
                int gp = atomicAdd(&cursor[b * 16], 1);
                if (gp < CAP) binned[(size_t)b * CAP + gp] = ent;
            }
        }
        __syncthreads();

        if (tid < NB) {
            int cnt = min(lcnt[tid], BCAP);
            gbase[tid] = atomicAdd(&cursor[tid * 16], cnt);
            lcnt[tid] = cnt;
        }
        __syncthreads();

        // wave w flushes buckets 4w..4w+3, lane-sequential -> coalesced lines
        int wave = tid >> 6, lane = tid & 63;
        for (int b = wave * 4; b < wave * 4 + 4; ++b) {
            int cnt = lcnt[b], gb = gbase[b];
            for (int i = lane; i < cnt; i += 64) {
                int gp = gb + i;
                if (gp < CAP) binned[(size_t)b * CAP + gp] = lbuf[b * BCAP + i];
            }
        }
        __syncthreads();
    }
}

// Phase B: LDS-accumulate one bucket slice (25 KB tile -> ~6 blocks/CU).
__global__ void accum_kernel(const uint2* __restrict__ binned,
                             const int* __restrict__ cursor,
                             float* __restrict__ partials) {
    __shared__ float acc[ROWS_PB];        // 25 KB
    int b = blockIdx.x / BPB;
    int s = blockIdx.x % BPB;
    for (int i = threadIdx.x; i < ROWS_PB; i += 256) acc[i] = 0.0f;
    __syncthreads();
    int count = min(cursor[b * 16], CAP);
    int start = (int)((long)count * s / BPB);
    int end   = (int)((long)count * (s + 1) / BPB);
    const uint2* src = binned + (size_t)b * CAP;
    int rowbase = b * ROWS_PB;
    for (int i = start + threadIdx.x; i < end; i += 256) {
        uint2 e = src[i];
        unsafeAtomicAdd(&acc[(int)e.x - rowbase], __uint_as_float(e.y));
    }
    __syncthreads();
    float* dst = partials + (size_t)blockIdx.x * ROWS_PB;
    for (int i = threadIdx.x; i < ROWS_PB; i += 256) dst[i] = acc[i];
}

// y[n] = sum over BPB partials of n's bucket
__global__ void reduce_kernel(const float* __restrict__ partials,
                              float* __restrict__ y) {
    int n = blockIdx.x * blockDim.x + threadIdx.x;
    if (n >= N_NODES) return;
    int b = n / ROWS_PB, loc = n - b * ROWS_PB;
    const float* p = partials + ((size_t)b * BPB) * ROWS_PB + loc;
    float acc = 0.0f;
#pragma unroll 8
    for (int s = 0; s < BPB; ++s) acc += p[(size_t)s * ROWS_PB];
    y[n] = acc;
}

// ---------- fallback path (R3): far-atomic scatter, used if ws too small ----
__global__ void edge_kernel_atomic(const int* __restrict__ rows,
                                   const int* __restrict__ cols,
                                   const float* __restrict__ vals,
                                   const float* __restrict__ Zt,
                                   float* __restrict__ yrep) {
    int t = blockIdx.x * blockDim.x + threadIdx.x;
    int base = t * 4;
    if (base >= KK * EE) return;
    int k = base / EE;
    const float* Zk = Zt + (size_t)k * N_NODES;
    float* y = yrep + (size_t)xcc_id() * N_NODES;
    int4 r = *(const int4*)(rows + base);
    int4 c = *(const int4*)(cols + base);
    float4 v = *(const float4*)(vals + base);
    unsafeAtomicAdd(&y[r.x], v.x * Zk[c.x]);
    unsafeAtomicAdd(&y[r.y], v.y * Zk[c.y]);
    unsafeAtomicAdd(&y[r.z], v.z * Zk[c.z]);
    unsafeAtomicAdd(&y[r.w], v.w * Zk[c.w]);
}

__global__ void reduce8_kernel(const float* __restrict__ yrep, float* __restrict__ y) {
    int n = blockIdx.x * blockDim.x + threadIdx.x;
    if (n >= N_NODES) return;
    float acc = 0.0f;
#pragma unroll
    for (int r = 0; r < NXCC; ++r) acc += yrep[(size_t)r * N_NODES + n];
    y[n] = acc;
}

extern "C" void kernel_launch(void* const* d_in, const int* in_sizes, int n_in,
                              void* d_out, int out_size, void* d_ws, size_t ws_size,
                              hipStream_t stream) {
    const float* X    = (const float*)d_in[0];
    const int*   rows = (const int*)  d_in[1];
    const int*   cols = (const int*)  d_in[2];
    const float* vals = (const float*)d_in[3];
    const float* h    = (const float*)d_in[4];
    float* y = (float*)d_out;

    char* ws = (char*)d_ws;
    float* Zt = (float*)ws;                                   // 2,000,000 B
    size_t cursor_off  = 2000000;
    size_t binned_off  = cursor_off + 1024;
    size_t binned_sz   = (size_t)NB * CAP * 8;                // 130,560,000 B
    size_t partial_off = binned_off + binned_sz;
    size_t partial_sz  = (size_t)NB * BPB * ROWS_PB * 4;      // 25,600,000 B
    size_t need = partial_off + partial_sz;                   // ~158.2 MB

    {   // Z = X @ h  (Zt layout [k][n])
        int threads = 256;
        int blocks  = (N_NODES + threads - 1) / threads;
        compute_z_kernel<<<blocks, threads, 0, stream>>>(X, h, Zt);
    }

    if (ws_size >= need) {
        int*   cursor   = (int*)(ws + cursor_off);
        uint2* binned   = (uint2*)(ws + binned_off);
        float* partials = (float*)(ws + partial_off);
        hipMemsetAsync(cursor, 0, 1024, stream);
        scatter_kernel<<<NCHUNK, 256, 0, stream>>>(rows, cols, vals, Zt, cursor, binned);
        accum_kernel<<<NB * BPB, 256, 0, stream>>>(binned, cursor, partials);
        {
            int threads = 256;
            int blocks  = (N_NODES + threads - 1) / threads;
            reduce_kernel<<<blocks, threads, 0, stream>>>(partials, y);
        }
    } else {
        // fallback: R3 far-atomic path
        float* yrep = (float*)(ws + cursor_off + 1024);
        hipMemsetAsync(yrep, 0, (size_t)NXCC * N_NODES * sizeof(float), stream);
        {
            int threads = 256;
            int blocks = ((KK * EE) / 4 + threads - 1) / threads;
            edge_kernel_atomic<<<blocks, threads, 0, stream>>>(rows, cols, vals, Zt, yrep);
        }
        {
            int threads = 256;
            int blocks  = (N_NODES + threads - 1) / threads;
            reduce8_kernel<<<blocks, threads, 0, stream>>>(yrep, y);
        }
    }
}

// Round 7
// 436.353 us; speedup vs baseline: 1.2333x; 1.2333x over previous
//
#include <hip/hip_runtime.h>
#include <hip/hip_fp16.h>

#define N_NODES 100000
#define KK 5
#define CC 16
#define EE 3200000
#define NXCC 8

#define NB 8                 // row buckets
#define ROWS_PB 12500        // N_NODES / NB
#define CAP 2100000          // per-bucket capacity (mean 2M, +75 sigma)
#define BPB 64               // accum blocks per bucket
#define CHUNK 5120           // edges per scatter block: 3125 * 5120 = 16,000,000
#define NCHUNK 3125
#define GROUPS 5             // CHUNK / (256*4)

__device__ __forceinline__ int xcc_id() {
    int x;
    asm volatile("s_getreg_b32 %0, hwreg(HW_REG_XCC_ID)" : "=s"(x));
    return x & (NXCC - 1);
}

// Kernel 1: Zt[k*N + n] = sum_c X[n,c] * h[c,k]
__global__ void compute_z_kernel(const float* __restrict__ X,
                                 const float* __restrict__ h,
                                 float* __restrict__ Zt) {
    int n = blockIdx.x * blockDim.x + threadIdx.x;
    if (n >= N_NODES) return;
    const float4* Xr = (const float4*)(X + (size_t)n * CC);
    float4 x0 = Xr[0], x1 = Xr[1], x2 = Xr[2], x3 = Xr[3];
    float xv[CC] = {x0.x, x0.y, x0.z, x0.w, x1.x, x1.y, x1.z, x1.w,
                    x2.x, x2.y, x2.z, x2.w, x3.x, x3.y, x3.z, x3.w};
#pragma unroll
    for (int k = 0; k < KK; ++k) {
        float acc = 0.0f;
#pragma unroll
        for (int c = 0; c < CC; ++c) acc += xv[c] * h[c * KK + k];
        Zt[k * N_NODES + n] = acc;
    }
}

// Phase A: 2-pass binning with WAVE-BALLOT aggregation (no per-edge LDS
// atomics, no round barriers). Entry = 4 B: [localrow:14][fp16 contrib:16].
// Lanes of one bucket write consecutive positions -> coalesced ~32B segments.
__global__ void scatter_kernel(const int* __restrict__ rows,
                               const int* __restrict__ cols,
                               const float* __restrict__ vals,
                               const float* __restrict__ Zt,
                               int* __restrict__ cursor,        // NB counters, stride 16 ints
                               unsigned int* __restrict__ binned) {
    __shared__ int bhist[NB], lbase[NB], lcnt[NB];
    int tid  = threadIdx.x;
    int lane = tid & 63;
    if (tid < NB) bhist[tid] = 0;
    __syncthreads();
    int cbase = blockIdx.x * CHUNK;
    int k = blockIdx.x / (EE / CHUNK);       // CHUNK | EE -> whole block shares one k
    const float* Zk = Zt + (size_t)k * N_NODES;

    // pass 1: per-wave ballot histogram (registers), 1 LDS atomic per bucket per wave
    int wcnt[NB];
#pragma unroll
    for (int b = 0; b < NB; ++b) wcnt[b] = 0;
#pragma unroll
    for (int g = 0; g < GROUPS; ++g) {
        int e = cbase + (g * 256 + tid) * 4;
        int4 r = *(const int4*)(rows + e);
        int rr[4] = {r.x, r.y, r.z, r.w};
#pragma unroll
        for (int i = 0; i < 4; ++i) {
            int b = rr[i] / ROWS_PB;
#pragma unroll
            for (int bb = 0; bb < NB; ++bb)
                wcnt[bb] += (int)__popcll(__ballot(b == bb));
        }
    }
    if (lane == 0) {
#pragma unroll
        for (int bb = 0; bb < NB; ++bb) atomicAdd(&bhist[bb], wcnt[bb]);
    }
    __syncthreads();
    if (tid < NB) {
        lbase[tid] = atomicAdd(&cursor[tid * 16], bhist[tid]);   // exact exclusive window
        lcnt[tid]  = 0;
    }
    __syncthreads();

    // pass 2: compute contrib, ballot-aggregate positions, coalesced store
#pragma unroll
    for (int g = 0; g < GROUPS; ++g) {
        int e = cbase + (g * 256 + tid) * 4;
        int4   r = *(const int4*)(rows + e);     // L1-hot (re-read of 20 KB chunk)
        int4   c = *(const int4*)(cols + e);
        float4 v = *(const float4*)(vals + e);
        int   rr[4] = {r.x, r.y, r.z, r.w};
        float cb[4] = {v.x * Zk[c.x], v.y * Zk[c.y], v.z * Zk[c.z], v.w * Zk[c.w]};
#pragma unroll
        for (int i = 0; i < 4; ++i) {
            int b = rr[i] / ROWS_PB;
            unsigned int packed = ((unsigned)(rr[i] - b * ROWS_PB) << 16) |
                                  (unsigned)__half_as_ushort(__float2half_rn(cb[i]));
#pragma unroll
            for (int bb = 0; bb < NB; ++bb) {
                unsigned long long mask = __ballot(b == bb);
                if (mask == 0ull) continue;               // wave-uniform branch
                int leader = __ffsll(mask) - 1;
                int cnt    = (int)__popcll(mask);
                int base;
                if (lane == leader) base = atomicAdd(&lcnt[bb], cnt);
                base = __shfl(base, leader, 64);
                if (b == bb) {
                    int rank = (int)__popcll(mask & ((1ull << lane) - 1ull));
                    int gp = lbase[bb] + base + rank;     // consecutive per bucket -> coalesced
                    if (gp < CAP)
                        binned[(size_t)bb * CAP + gp] = packed;
                }
            }
        }
    }
}

// Phase B: LDS-accumulate one bucket slice, write dense partial (no global atomics).
__global__ void accum_kernel(const unsigned int* __restrict__ binned,
                             const int* __restrict__ cursor,
                             float* __restrict__ partials) {
    __shared__ float acc[ROWS_PB];               // 50 KB -> 3 blocks/CU
    int b = blockIdx.x / BPB;
    int s = blockIdx.x % BPB;
    for (int i = threadIdx.x; i < ROWS_PB; i += 256) acc[i] = 0.0f;
    __syncthreads();
    int count = min(cursor[b * 16], CAP);
    int start = (int)((long)count * s / BPB);
    int end   = (int)((long)count * (s + 1) / BPB);
    const unsigned int* src = binned + (size_t)b * CAP;
    for (int i = start + threadIdx.x; i < end; i += 256) {
        unsigned int e = src[i];
        float v = __half2float(__ushort_as_half((unsigned short)(e & 0xFFFFu)));
        atomicAdd(&acc[e >> 16], v);             // native ds_add_f32
    }
    __syncthreads();
    float* dst = partials + (size_t)blockIdx.x * ROWS_PB;
    for (int i = threadIdx.x; i < ROWS_PB; i += 256) dst[i] = acc[i];
}

// y[n] = sum over BPB partials of n's bucket
__global__ void reduce_kernel(const float* __restrict__ partials,
                              float* __restrict__ y) {
    int n = blockIdx.x * blockDim.x + threadIdx.x;
    if (n >= N_NODES) return;
    int b = n / ROWS_PB, loc = n - b * ROWS_PB;
    const float* p = partials + ((size_t)b * BPB) * ROWS_PB + loc;
    float acc = 0.0f;
#pragma unroll 8
    for (int s = 0; s < BPB; ++s) acc += p[(size_t)s * ROWS_PB];
    y[n] = acc;
}

// ---------- fallback path (R3): far-atomic scatter, used if ws too small ----
__global__ void edge_kernel_atomic(const int* __restrict__ rows,
                                   const int* __restrict__ cols,
                                   const float* __restrict__ vals,
                                   const float* __restrict__ Zt,
                                   float* __restrict__ yrep) {
    int t = blockIdx.x * blockDim.x + threadIdx.x;
    int base = t * 4;
    if (base >= KK * EE) return;
    int k = base / EE;
    const float* Zk = Zt + (size_t)k * N_NODES;
    float* y = yrep + (size_t)xcc_id() * N_NODES;
    int4 r = *(const int4*)(rows + base);
    int4 c = *(const int4*)(cols + base);
    float4 v = *(const float4*)(vals + base);
    unsafeAtomicAdd(&y[r.x], v.x * Zk[c.x]);
    unsafeAtomicAdd(&y[r.y], v.y * Zk[c.y]);
    unsafeAtomicAdd(&y[r.z], v.z * Zk[c.z]);
    unsafeAtomicAdd(&y[r.w], v.w * Zk[c.w]);
}

__global__ void reduce8_kernel(const float* __restrict__ yrep, float* __restrict__ y) {
    int n = blockIdx.x * blockDim.x + threadIdx.x;
    if (n >= N_NODES) return;
    float acc = 0.0f;
#pragma unroll
    for (int r = 0; r < NXCC; ++r) acc += yrep[(size_t)r * N_NODES + n];
    y[n] = acc;
}

extern "C" void kernel_launch(void* const* d_in, const int* in_sizes, int n_in,
                              void* d_out, int out_size, void* d_ws, size_t ws_size,
                              hipStream_t stream) {
    const float* X    = (const float*)d_in[0];
    const int*   rows = (const int*)  d_in[1];
    const int*   cols = (const int*)  d_in[2];
    const float* vals = (const float*)d_in[3];
    const float* h    = (const float*)d_in[4];
    float* y = (float*)d_out;

    char* ws = (char*)d_ws;
    float* Zt = (float*)ws;                                   // 2,000,000 B
    size_t cursor_off  = 2000000;
    size_t binned_off  = cursor_off + 1024;
    size_t binned_sz   = (size_t)NB * CAP * 4;                // 67,200,000 B
    size_t partial_off = binned_off + binned_sz;
    size_t partial_sz  = (size_t)NB * BPB * ROWS_PB * 4;      // 25,600,000 B
    size_t need = partial_off + partial_sz;                   // ~94.8 MB

    {   // Z = X @ h  (Zt layout [k][n])
        int threads = 256;
        int blocks  = (N_NODES + threads - 1) / threads;
        compute_z_kernel<<<blocks, threads, 0, stream>>>(X, h, Zt);
    }

    if (ws_size >= need) {
        int*          cursor   = (int*)(ws + cursor_off);
        unsigned int* binned   = (unsigned int*)(ws + binned_off);
        float*        partials = (float*)(ws + partial_off);
        hipMemsetAsync(cursor, 0, 1024, stream);
        scatter_kernel<<<NCHUNK, 256, 0, stream>>>(rows, cols, vals, Zt, cursor, binned);
        accum_kernel<<<NB * BPB, 256, 0, stream>>>(binned, cursor, partials);
        {
            int threads = 256;
            int blocks  = (N_NODES + threads - 1) / threads;
            reduce_kernel<<<blocks, threads, 0, stream>>>(partials, y);
        }
    } else {
        // fallback: R3 far-atomic path
        float* yrep = (float*)(ws + cursor_off + 1024);
        hipMemsetAsync(yrep, 0, (size_t)NXCC * N_NODES * sizeof(float), stream);
        {
            int threads = 256;
            int blocks = ((KK * EE) / 4 + threads - 1) / threads;
            edge_kernel_atomic<<<blocks, threads, 0, stream>>>(rows, cols, vals, Zt, yrep);
        }
        {
            int threads = 256;
            int blocks  = (N_NODES + threads - 1) / threads;
            reduce8_kernel<<<blocks, threads, 0, stream>>>(yrep, y);
        }
    }
}

// Round 8
// 397.076 us; speedup vs baseline: 1.3553x; 1.0989x over previous
//
#include <hip/hip_runtime.h>
#include <hip/hip_fp16.h>

#define N_NODES 100000
#define KK 5
#define CC 16
#define EE 3200000
#define NXCC 8

#define NB 16                // row buckets
#define ROWS_PB 6250         // N_NODES / NB
#define WCAP 512             // entries per (block,bucket) window: mean 320, +11 sigma
#define BPB 96               // accum blocks per bucket (16*96 = 1536 blocks, 6/CU)
#define CHUNK 5120           // edges per scatter block
#define NCHUNK 3125          // 3125 * 5120 = 16,000,000
#define GROUPS 5             // CHUNK / (256*4)
#define BLK_PER_K 625        // EE / CHUNK

__device__ __forceinline__ int xcc_id() {
    int x;
    asm volatile("s_getreg_b32 %0, hwreg(HW_REG_XCC_ID)" : "=s"(x));
    return x & (NXCC - 1);
}

// Kernel 1: Zt[k*N + n] = sum_c X[n,c] * h[c,k]
__global__ void compute_z_kernel(const float* __restrict__ X,
                                 const float* __restrict__ h,
                                 float* __restrict__ Zt) {
    int n = blockIdx.x * blockDim.x + threadIdx.x;
    if (n >= N_NODES) return;
    const float4* Xr = (const float4*)(X + (size_t)n * CC);
    float4 x0 = Xr[0], x1 = Xr[1], x2 = Xr[2], x3 = Xr[3];
    float xv[CC] = {x0.x, x0.y, x0.z, x0.w, x1.x, x1.y, x1.z, x1.w,
                    x2.x, x2.y, x2.z, x2.w, x3.x, x3.y, x3.z, x3.w};
#pragma unroll
    for (int k = 0; k < KK; ++k) {
        float acc = 0.0f;
#pragma unroll
        for (int c = 0; c < CC; ++c) acc += xv[c] * h[c * KK + k];
        Zt[k * N_NODES + n] = acc;
    }
}

// Phase A (single pass, no histogram, no ballots): each block owns a fixed
// window of WCAP entries per bucket. One LDS atomic per edge for the position;
// per-wave returned positions are contiguous per bucket -> stores coalesce.
// Entry = 4 B: [localrow:13]<<16 | fp16(contrib). Overflow (statistically
// never: +11 sigma) spills exactly via far-atomic into dense spill[].
__global__ void scatter_kernel(const int* __restrict__ rows,
                               const int* __restrict__ cols,
                               const float* __restrict__ vals,
                               const float* __restrict__ Zt,
                               unsigned int* __restrict__ binned,
                               int* __restrict__ counts,
                               float* __restrict__ spill) {
    __shared__ int lcnt[NB];
    int tid = threadIdx.x;
    if (tid < NB) lcnt[tid] = 0;
    __syncthreads();

    int w = blockIdx.x;
    int cbase = w * CHUNK;
    const float* Zk = Zt + (size_t)(w / BLK_PER_K) * N_NODES;   // block shares one k
    unsigned int* wbase = binned + (size_t)w * (NB * WCAP);

#pragma unroll
    for (int g = 0; g < GROUPS; ++g) {
        int e = cbase + (g * 256 + tid) * 4;
        int4   r = *(const int4*)(rows + e);
        int4   c = *(const int4*)(cols + e);
        float4 v = *(const float4*)(vals + e);
        int   rr[4] = {r.x, r.y, r.z, r.w};
        float cb[4] = {v.x * Zk[c.x], v.y * Zk[c.y], v.z * Zk[c.z], v.w * Zk[c.w]};
#pragma unroll
        for (int i = 0; i < 4; ++i) {
            int b = rr[i] / ROWS_PB;                  // compiler magic-mul
            int pos = atomicAdd(&lcnt[b], 1);
            if (pos < WCAP) {
                unsigned int packed =
                    ((unsigned)(rr[i] - b * ROWS_PB) << 16) |
                    (unsigned)__half_as_ushort(__float2half_rn(cb[i]));
                wbase[b * WCAP + pos] = packed;
            } else {
                unsafeAtomicAdd(&spill[rr[i]], cb[i]);   // exact, ~never taken
            }
        }
    }
    __syncthreads();
    if (tid < NB) counts[w * NB + tid] = min(lcnt[tid], WCAP);
}

// Phase B: bucket b, slice s of scatter-block windows; LDS accumulate (25 KB
// -> ~6 blocks/CU), dense partial writeout, zero global atomics.
__global__ void accum_kernel(const unsigned int* __restrict__ binned,
                             const int* __restrict__ counts,
                             float* __restrict__ partials) {
    __shared__ float acc[ROWS_PB];                    // 25 KB
    int b = blockIdx.x / BPB;
    int s = blockIdx.x % BPB;
    int tid = threadIdx.x;
    for (int i = tid; i < ROWS_PB; i += 256) acc[i] = 0.0f;
    __syncthreads();

    int wlo = (NCHUNK * s) / BPB;
    int whi = (NCHUNK * (s + 1)) / BPB;
    for (int w = wlo; w < whi; ++w) {
        int cnt = counts[w * NB + b];                 // wave-uniform -> broadcast
        const unsigned int* src = binned + (size_t)w * (NB * WCAP) + b * WCAP;
        for (int i = tid; i < cnt; i += 256) {
            unsigned int e = src[i];
            float v = __half2float(__ushort_as_half((unsigned short)(e & 0xFFFFu)));
            atomicAdd(&acc[e >> 16], v);              // ds_add_f32
        }
    }
    __syncthreads();
    float* dst = partials + (size_t)blockIdx.x * ROWS_PB;
    for (int i = tid; i < ROWS_PB; i += 256) dst[i] = acc[i];
}

// y[n] = spill[n] + sum over BPB partial slices of n's bucket
__global__ void reduce_kernel(const float* __restrict__ partials,
                              const float* __restrict__ spill,
                              float* __restrict__ y) {
    int n = blockIdx.x * blockDim.x + threadIdx.x;
    if (n >= N_NODES) return;
    int b = n / ROWS_PB, loc = n - b * ROWS_PB;
    const float* p = partials + (size_t)(b * BPB) * ROWS_PB + loc;
    float acc = spill[n];
#pragma unroll 8
    for (int s = 0; s < BPB; ++s) acc += p[(size_t)s * ROWS_PB];
    y[n] = acc;
}

// ---------- fallback path (R3): far-atomic scatter, used if ws too small ----
__global__ void edge_kernel_atomic(const int* __restrict__ rows,
                                   const int* __restrict__ cols,
                                   const float* __restrict__ vals,
                                   const float* __restrict__ Zt,
                                   float* __restrict__ yrep) {
    int t = blockIdx.x * blockDim.x + threadIdx.x;
    int base = t * 4;
    if (base >= KK * EE) return;
    int k = base / EE;
    const float* Zk = Zt + (size_t)k * N_NODES;
    float* y = yrep + (size_t)xcc_id() * N_NODES;
    int4 r = *(const int4*)(rows + base);
    int4 c = *(const int4*)(cols + base);
    float4 v = *(const float4*)(vals + base);
    unsafeAtomicAdd(&y[r.x], v.x * Zk[c.x]);
    unsafeAtomicAdd(&y[r.y], v.y * Zk[c.y]);
    unsafeAtomicAdd(&y[r.z], v.z * Zk[c.z]);
    unsafeAtomicAdd(&y[r.w], v.w * Zk[c.w]);
}

__global__ void reduce8_kernel(const float* __restrict__ yrep, float* __restrict__ y) {
    int n = blockIdx.x * blockDim.x + threadIdx.x;
    if (n >= N_NODES) return;
    float acc = 0.0f;
#pragma unroll
    for (int r = 0; r < NXCC; ++r) acc += yrep[(size_t)r * N_NODES + n];
    y[n] = acc;
}

extern "C" void kernel_launch(void* const* d_in, const int* in_sizes, int n_in,
                              void* d_out, int out_size, void* d_ws, size_t ws_size,
                              hipStream_t stream) {
    const float* X    = (const float*)d_in[0];
    const int*   rows = (const int*)  d_in[1];
    const int*   cols = (const int*)  d_in[2];
    const float* vals = (const float*)d_in[3];
    const float* h    = (const float*)d_in[4];
    float* y = (float*)d_out;

    char* ws = (char*)d_ws;
    float* Zt = (float*)ws;                                    //  2,000,000 B
    size_t counts_off  = 2000000;                              //    200,000 B
    size_t spill_off   = counts_off + 200000;                  //    400,000 B
    size_t binned_off  = spill_off + 400000;
    size_t binned_sz   = (size_t)NCHUNK * NB * WCAP * 4;       // 102,400,000 B
    size_t partial_off = binned_off + binned_sz;
    size_t partial_sz  = (size_t)NB * BPB * ROWS_PB * 4;       //  38,400,000 B
    size_t need = partial_off + partial_sz;                    // ~143.4 MB

    {   // Z = X @ h  (Zt layout [k][n])
        int threads = 256;
        int blocks  = (N_NODES + threads - 1) / threads;
        compute_z_kernel<<<blocks, threads, 0, stream>>>(X, h, Zt);
    }

    if (ws_size >= need) {
        int*          counts   = (int*)(ws + counts_off);
        float*        spill    = (float*)(ws + spill_off);
        unsigned int* binned   = (unsigned int*)(ws + binned_off);
        float*        partials = (float*)(ws + partial_off);
        hipMemsetAsync(spill, 0, 400000, stream);
        scatter_kernel<<<NCHUNK, 256, 0, stream>>>(rows, cols, vals, Zt,
                                                   binned, counts, spill);
        accum_kernel<<<NB * BPB, 256, 0, stream>>>(binned, counts, partials);
        {
            int threads = 256;
            int blocks  = (N_NODES + threads - 1) / threads;
            reduce_kernel<<<blocks, threads, 0, stream>>>(partials, spill, y);
        }
    } else {
        // fallback: R3 far-atomic path
        float* yrep = (float*)(ws + spill_off);
        hipMemsetAsync(yrep, 0, (size_t)NXCC * N_NODES * sizeof(float), stream);
        {
            int threads = 256;
            int blocks = ((KK * EE) / 4 + threads - 1) / threads;
            edge_kernel_atomic<<<blocks, threads, 0, stream>>>(rows, cols, vals, Zt, yrep);
        }
        {
            int threads = 256;
            int blocks  = (N_NODES + threads - 1) / threads;
            reduce8_kernel<<<blocks, threads, 0, stream>>>(yrep, y);
        }
    }
}